// Round 3
// baseline (1135.412 us; speedup 1.0000x reference)
//
#include <hip/hip_runtime.h>
#include <hip/hip_bf16.h>
#include <cstdint>
#include <cstddef>

#define DI __device__ __forceinline__

typedef __bf16 bf16_t;
typedef bf16_t bf16x8 __attribute__((ext_vector_type(8)));
typedef float f32x4 __attribute__((ext_vector_type(4)));

constexpr int Vn = 4, Bn = 2, Hn = 32, Wn = 64, Zn = 13, Cn = 256, HIDn = 1024;
constexpr int Ln = Hn * Wn * Zn;                 // 26624
constexpr int BWn = Bn * (Hn / 4) * (Wn / 4) * Zn; // 3328 windows (B_)
constexpr int PB = Bn * Ln;                      // 53248 rows per variable
constexpr int ROWS = Vn * PB;                    // 212992

// ---------- global -> LDS direct staging (16B per lane) ----------
DI void gload_lds16(const void* g, void* l) {
  __builtin_amdgcn_global_load_lds(
      (const __attribute__((address_space(1))) void*)g,
      (__attribute__((address_space(3))) void*)l, 16, 0, 0);
}

DI unsigned short f2bf_bits(float f) {
  __hip_bfloat16 h = __float2bfloat16(f);
  return *reinterpret_cast<unsigned short*>(&h);
}

// ---------- weight transpose: src [V][K][N] f32 -> dst [V][N][K] bf16 ----------
__global__ __launch_bounds__(256) void transpose_w_kernel(
    const float* __restrict__ src, __hip_bfloat16* __restrict__ dst, int K, int N) {
  int i = blockIdx.x * 256 + threadIdx.x;
  int total = Vn * K * N;
  if (i >= total) return;
  int k = i % K;
  int t = i / K;
  int n = t % N;
  int v = t / N;
  dst[i] = __float2bfloat16(src[((size_t)v * K + k) * N + n]);
}

// ---------- LN1 fused with cyclic shift + window partition ----------
__global__ __launch_bounds__(256) void ln1_kernel(
    const float* __restrict__ x0, const float* __restrict__ x1,
    const float* __restrict__ x2i, const float* __restrict__ x3,
    const float* __restrict__ g_, const float* __restrict__ b_,
    __hip_bfloat16* __restrict__ xw) {
  int gw = blockIdx.x * 4 + (threadIdx.x >> 6);
  int lane = threadIdx.x & 63;
  int v = gw / PB;
  int rem = gw - v * PB;
  int bw = rem >> 4, nn = rem & 15;
  int zb = bw % 13;
  int t = bw / 13;
  int wb = t & 15, t2 = t >> 4;
  int hb = t2 & 7, b = t2 >> 3;
  int hs = (hb * 4 + (nn >> 2) + 30) & 31;   // (h - 2) mod 32
  int wsrc = (wb * 4 + (nn & 3) + 62) & 63;  // (w - 2) mod 64
  size_t l = (size_t)(hs * 64 + wsrc) * 13 + zb;
  const float* xv = (v == 0) ? x0 : (v == 1) ? x1 : (v == 2) ? x2i : x3;
  const float* xp = xv + ((size_t)b * Ln + l) * 256;
  float4 val = *(const float4*)(xp + lane * 4);
  float s = val.x + val.y + val.z + val.w;
  float sq = val.x * val.x + val.y * val.y + val.z * val.z + val.w * val.w;
#pragma unroll
  for (int o = 32; o; o >>= 1) {
    s += __shfl_xor(s, o);
    sq += __shfl_xor(sq, o);
  }
  float mean = s * (1.0f / 256.0f);
  float var = sq * (1.0f / 256.0f) - mean * mean;
  float rstd = rsqrtf(var + 1e-5f);
  const float* gg = g_ + v * 256 + lane * 4;
  const float* bb = b_ + v * 256 + lane * 4;
  ushort4 o4;
  o4.x = f2bf_bits((val.x - mean) * rstd * gg[0] + bb[0]);
  o4.y = f2bf_bits((val.y - mean) * rstd * gg[1] + bb[1]);
  o4.z = f2bf_bits((val.z - mean) * rstd * gg[2] + bb[2]);
  o4.w = f2bf_bits((val.w - mean) * rstd * gg[3] + bb[3]);
  *reinterpret_cast<ushort4*>(xw + (size_t)gw * 256 + lane * 4) = o4;
}

// ---------- LN2 (straight rows, x2 lives in d_out) ----------
__global__ __launch_bounds__(256) void ln2_kernel(
    const float* __restrict__ x2, const float* __restrict__ g_,
    const float* __restrict__ b_, __hip_bfloat16* __restrict__ xm) {
  int r = blockIdx.x * 4 + (threadIdx.x >> 6);
  int lane = threadIdx.x & 63;
  int v = r / PB;
  const float* xp = x2 + (size_t)r * 256;
  float4 val = *(const float4*)(xp + lane * 4);
  float s = val.x + val.y + val.z + val.w;
  float sq = val.x * val.x + val.y * val.y + val.z * val.z + val.w * val.w;
#pragma unroll
  for (int o = 32; o; o >>= 1) {
    s += __shfl_xor(s, o);
    sq += __shfl_xor(sq, o);
  }
  float mean = s * (1.0f / 256.0f);
  float var = sq * (1.0f / 256.0f) - mean * mean;
  float rstd = rsqrtf(var + 1e-5f);
  const float* gg = g_ + v * 256 + lane * 4;
  const float* bb = b_ + v * 256 + lane * 4;
  ushort4 o4;
  o4.x = f2bf_bits((val.x - mean) * rstd * gg[0] + bb[0]);
  o4.y = f2bf_bits((val.y - mean) * rstd * gg[1] + bb[1]);
  o4.z = f2bf_bits((val.z - mean) * rstd * gg[2] + bb[2]);
  o4.w = f2bf_bits((val.w - mean) * rstd * gg[3] + bb[3]);
  *reinterpret_cast<ushort4*>(xm + (size_t)r * 256 + lane * 4) = o4;
}

// ---------- windowed attention (unchanged, verified) ----------
__global__ __launch_bounds__(256) void attn_kernel(
    const __hip_bfloat16* __restrict__ qkvp, __hip_bfloat16* __restrict__ ctx) {
  __shared__ float P[4][16][17];
  int b_ = blockIdx.x;
  int v = blockIdx.y;
  int wid = threadIdx.x >> 6, lane = threadIdx.x & 63;
  int lm = lane & 15, hi = lane >> 4;
  const bf16_t* base = (const bf16_t*)qkvp + (size_t)(v * BWn + b_) * 16 * 768;
  const float scale = 0.17677669529663687f;  // 32^-0.5
  f32x4 zero = {0.f, 0.f, 0.f, 0.f};
#pragma unroll
  for (int hh = 0; hh < 2; ++hh) {
    int h = wid + 4 * hh;
    bf16x8 qf = *(const bf16x8*)(base + (size_t)lm * 768 + h * 32 + hi * 8);
    bf16x8 kf = *(const bf16x8*)(base + (size_t)lm * 768 + 256 + h * 32 + hi * 8);
    f32x4 s = __builtin_amdgcn_mfma_f32_16x16x32_bf16(qf, kf, zero, 0, 0, 0);
    float p0[4];
#pragma unroll
    for (int q = 0; q < 4; ++q) {
      float val = s[q] * scale;
      float mx = val;
#pragma unroll
      for (int o = 8; o >= 1; o >>= 1) mx = fmaxf(mx, __shfl_xor(mx, o));
      float e = expf(val - mx);
      float sum = e;
#pragma unroll
      for (int o = 8; o >= 1; o >>= 1) sum += __shfl_xor(sum, o);
      p0[q] = e / sum;
    }
#pragma unroll
    for (int q = 0; q < 4; ++q) P[wid][hi * 4 + q][lm] = p0[q];
    bf16x8 pa;
#pragma unroll
    for (int j = 0; j < 8; ++j) pa[j] = (bf16_t)0.f;
    if (hi < 2) {
#pragma unroll
      for (int j = 0; j < 8; ++j) pa[j] = (bf16_t)P[wid][lm][hi * 8 + j];
    }
#pragma unroll
    for (int dh = 0; dh < 2; ++dh) {
      bf16x8 vf;
#pragma unroll
      for (int j = 0; j < 8; ++j) vf[j] = (bf16_t)0.f;
      if (hi < 2) {
#pragma unroll
        for (int j = 0; j < 8; ++j)
          vf[j] = base[(size_t)(hi * 8 + j) * 768 + 512 + h * 32 + dh * 16 + lm];
      }
      f32x4 c = __builtin_amdgcn_mfma_f32_16x16x32_bf16(pa, vf, zero, 0, 0, 0);
#pragma unroll
      for (int q = 0; q < 4; ++q) {
        int n = hi * 4 + q;
        int d = dh * 16 + lm;
        int r = n * 4 + v;
        int vo = r >> 4, no = r & 15;
        ctx[((size_t)(vo * BWn + b_) * 16 + no) * 256 + h * 32 + d] = __float2bfloat16(c[q]);
      }
    }
  }
}

// ---------- GEMM v3: 128x128 tile, 4 waves (2x2), BK=64, 64KB LDS -> 2 blocks/CU,
// counted-vmcnt double-buffer (loads never drain in main loop), grid x=colTile y=rowPanel.
// A [V*PB, K] row-major bf16, WT [V, N, K] bf16 (pre-transposed).
// EPI: 0 = qkv (bias, bf16 out), 1 = proj (bias + window-reverse + roll + shortcut -> f32 x2),
//      2 = fc1 (bias + exact GELU, bf16 out), 3 = fc2 (bias + x2 residual RMW -> f32 out)
template <int EPI, int K, int N>
__global__ __launch_bounds__(256, 2) void gemm3(
    const __hip_bfloat16* __restrict__ A, const __hip_bfloat16* __restrict__ WT,
    const float* __restrict__ bias, __hip_bfloat16* __restrict__ outb,
    float* __restrict__ outf, const float* __restrict__ xi0,
    const float* __restrict__ xi1, const float* __restrict__ xi2,
    const float* __restrict__ xi3) {
  constexpr int NT = K / 64;
  const int v = blockIdx.z;
  const int colBase = blockIdx.x * 128;
  const int rowBase = blockIdx.y * 128;
  const bf16_t* Av = (const bf16_t*)A + ((size_t)v * PB + rowBase) * K;
  const bf16_t* Wv = (const bf16_t*)WT + ((size_t)v * N + colBase) * K;
  __shared__ __align__(16) bf16_t As[2][128][64];
  __shared__ __align__(16) bf16_t Bs[2][128][64];
  const int tid = threadIdx.x, wid = tid >> 6, lane = tid & 63;
  const int wr = wid >> 1, wc = wid & 1;  // 2x2 wave grid, each wave 64x64
  const int lm = lane & 15, hi = lane >> 4;
  const int rA = lane >> 3;              // 0..7 row within 8-row staging group
  const int lg = (lane & 7) ^ rA;        // swizzled source granule (16B units)

  f32x4 acc[4][4];
#pragma unroll
  for (int m = 0; m < 4; ++m)
#pragma unroll
    for (int n = 0; n < 4; ++n) acc[m][n] = f32x4{0.f, 0.f, 0.f, 0.f};

  auto stage = [&](int buf, int kt) {
    // 16 groups of 8 rows each for A and B; 4 groups per wave; 8 gload_lds per wave total.
#pragma unroll
    for (int g = 0; g < 4; ++g) {
      int grp = wid * 4 + g;
      gload_lds16(Av + (size_t)(grp * 8 + rA) * K + kt + lg * 8, &As[buf][grp * 8][0]);
    }
#pragma unroll
    for (int g = 0; g < 4; ++g) {
      int grp = wid * 4 + g;
      gload_lds16(Wv + (size_t)(grp * 8 + rA) * K + kt + lg * 8, &Bs[buf][grp * 8][0]);
    }
  };

  stage(0, 0);
#pragma unroll
  for (int t = 0; t < NT; ++t) {
    const int cur = t & 1;
    if (t + 1 < NT) {
      stage(cur ^ 1, (t + 1) * 64);
      // wait only tile t's 8 loads (oldest); tile t+1's 8 stay in flight across the barrier
      asm volatile("s_waitcnt vmcnt(8)" ::: "memory");
    } else {
      asm volatile("s_waitcnt vmcnt(0)" ::: "memory");
    }
    __builtin_amdgcn_s_barrier();
    __builtin_amdgcn_sched_barrier(0);
#pragma unroll
    for (int kk = 0; kk < 2; ++kk) {
      bf16x8 af[4], bfv[4];
#pragma unroll
      for (int m = 0; m < 4; ++m) {
        const int r = wr * 64 + m * 16 + lm;
        af[m] = *(const bf16x8*)&As[cur][r][((kk * 4 + hi) ^ (lm & 7)) * 8];
      }
#pragma unroll
      for (int n = 0; n < 4; ++n) {
        const int r = wc * 64 + n * 16 + lm;
        bfv[n] = *(const bf16x8*)&Bs[cur][r][((kk * 4 + hi) ^ (lm & 7)) * 8];
      }
#pragma unroll
      for (int m = 0; m < 4; ++m)
#pragma unroll
        for (int n = 0; n < 4; ++n)
          acc[m][n] = __builtin_amdgcn_mfma_f32_16x16x32_bf16(af[m], bfv[n], acc[m][n], 0, 0, 0);
    }
    __builtin_amdgcn_sched_barrier(0);
    asm volatile("s_waitcnt lgkmcnt(0)" ::: "memory");
    __builtin_amdgcn_s_barrier();
  }

// epilogue: C/D layout col = lane&15, row = (lane>>4)*4 + reg
#pragma unroll
  for (int m = 0; m < 4; ++m) {
#pragma unroll
    for (int q = 0; q < 4; ++q) {
      const int rowv = rowBase + wr * 64 + m * 16 + hi * 4 + q;
      if constexpr (EPI == 1) {
        int b_ = rowv >> 4, nn = rowv & 15;
        int zb = b_ % 13;
        int t = b_ / 13;
        int wb = t & 15, t2 = t >> 4;
        int hb = t2 & 7, bb = t2 >> 3;
        int h2 = (hb * 4 + (nn >> 2) + 2) & 31;  // window reverse + roll(+2)
        int w2 = (wb * 4 + (nn & 3) + 2) & 63;
        size_t l = (size_t)(h2 * 64 + w2) * 13 + zb;
        const float* xv = (v == 0) ? xi0 : (v == 1) ? xi1 : (v == 2) ? xi2 : xi3;
        const float* xs = xv + ((size_t)bb * Ln + l) * 256;
        float* dst = outf + (((size_t)v * Bn + bb) * Ln + l) * 256;
#pragma unroll
        for (int n = 0; n < 4; ++n) {
          int gcol = colBase + wc * 64 + n * 16 + lm;
          dst[gcol] = xs[gcol] + acc[m][n][q] + bias[v * N + gcol];
        }
      } else if constexpr (EPI == 3) {
        float* o = outf + ((size_t)v * PB + rowv) * 256;
#pragma unroll
        for (int n = 0; n < 4; ++n) {
          int gcol = colBase + wc * 64 + n * 16 + lm;
          o[gcol] = o[gcol] + acc[m][n][q] + bias[v * N + gcol];
        }
      } else {
        __hip_bfloat16* o = outb + ((size_t)v * PB + rowv) * N;
#pragma unroll
        for (int n = 0; n < 4; ++n) {
          int gcol = colBase + wc * 64 + n * 16 + lm;
          float val = acc[m][n][q] + bias[v * N + gcol];
          if constexpr (EPI == 2)
            val = 0.5f * val * (1.0f + erff(val * 0.70710678118654752f));
          o[gcol] = __float2bfloat16(val);
        }
      }
    }
  }
}

extern "C" void kernel_launch(void* const* d_in, const int* in_sizes, int n_in,
                              void* d_out, int out_size, void* d_ws, size_t ws_size,
                              hipStream_t stream) {
  const float* x0 = (const float*)d_in[0];
  const float* x1 = (const float*)d_in[1];
  const float* x2i = (const float*)d_in[2];
  const float* x3 = (const float*)d_in[3];
  const float* qkv_w = (const float*)d_in[4];
  const float* qkv_b = (const float*)d_in[5];
  const float* proj_w = (const float*)d_in[6];
  const float* proj_b = (const float*)d_in[7];
  const float* n1g = (const float*)d_in[8];
  const float* n1b = (const float*)d_in[9];
  const float* n2g = (const float*)d_in[10];
  const float* n2b = (const float*)d_in[11];
  const float* fc1_w = (const float*)d_in[12];
  const float* fc1_b = (const float*)d_in[13];
  const float* fc2_w = (const float*)d_in[14];
  const float* fc2_b = (const float*)d_in[15];
  float* out = (float*)d_out;  // doubles as x2 buffer

  uint8_t* ws = (uint8_t*)d_ws;
  size_t off = 0;
  auto alloc = [&](size_t bytes) -> void* {
    void* p = ws + off;
    off += (bytes + 255) & ~(size_t)255;
    return p;
  };
  __hip_bfloat16* wqkvT = (__hip_bfloat16*)alloc((size_t)Vn * Cn * 768 * 2);
  __hip_bfloat16* wprojT = (__hip_bfloat16*)alloc((size_t)Vn * Cn * Cn * 2);
  __hip_bfloat16* wfc1T = (__hip_bfloat16*)alloc((size_t)Vn * Cn * HIDn * 2);
  __hip_bfloat16* wfc2T = (__hip_bfloat16*)alloc((size_t)Vn * HIDn * Cn * 2);
  __hip_bfloat16* xw = (__hip_bfloat16*)alloc((size_t)ROWS * Cn * 2);     // xw / ctx / xm
  __hip_bfloat16* qkvb = (__hip_bfloat16*)alloc((size_t)ROWS * HIDn * 2); // qkv / h

  {
    int tot = Vn * Cn * 768;
    transpose_w_kernel<<<(tot + 255) / 256, 256, 0, stream>>>(qkv_w, wqkvT, Cn, 768);
  }
  {
    int tot = Vn * Cn * Cn;
    transpose_w_kernel<<<(tot + 255) / 256, 256, 0, stream>>>(proj_w, wprojT, Cn, Cn);
  }
  {
    int tot = Vn * Cn * HIDn;
    transpose_w_kernel<<<(tot + 255) / 256, 256, 0, stream>>>(fc1_w, wfc1T, Cn, HIDn);
  }
  {
    int tot = Vn * HIDn * Cn;
    transpose_w_kernel<<<(tot + 255) / 256, 256, 0, stream>>>(fc2_w, wfc2T, HIDn, Cn);
  }

  ln1_kernel<<<ROWS / 4, 256, 0, stream>>>(x0, x1, x2i, x3, n1g, n1b, xw);

  gemm3<0, 256, 768><<<dim3(6, PB / 128, Vn), 256, 0, stream>>>(
      xw, wqkvT, qkv_b, qkvb, nullptr, nullptr, nullptr, nullptr, nullptr);

  attn_kernel<<<dim3(BWn, Vn), 256, 0, stream>>>(qkvb, xw /*ctx*/);

  gemm3<1, 256, 256><<<dim3(2, PB / 128, Vn), 256, 0, stream>>>(
      xw /*ctx*/, wprojT, proj_b, nullptr, out /*x2*/, x0, x1, x2i, x3);

  ln2_kernel<<<ROWS / 4, 256, 0, stream>>>(out /*x2*/, n2g, n2b, xw /*xm*/);

  gemm3<2, 256, 1024><<<dim3(8, PB / 128, Vn), 256, 0, stream>>>(
      xw /*xm*/, wfc1T, fc1_b, qkvb /*h*/, nullptr, nullptr, nullptr, nullptr, nullptr);

  gemm3<3, 1024, 256><<<dim3(2, PB / 128, Vn), 256, 0, stream>>>(
      qkvb /*h*/, wfc2T, fc2_b, nullptr, out, nullptr, nullptr, nullptr, nullptr);
}

// Round 4
// 956.884 us; speedup vs baseline: 1.1866x; 1.1866x over previous
//
#include <hip/hip_runtime.h>
#include <hip/hip_bf16.h>
#include <cstdint>
#include <cstddef>

#define DI __device__ __forceinline__

typedef __bf16 bf16_t;
typedef bf16_t bf16x8 __attribute__((ext_vector_type(8)));
typedef float f32x4 __attribute__((ext_vector_type(4)));

constexpr int Vn = 4, Bn = 2, Hn = 32, Wn = 64, Zn = 13, Cn = 256, HIDn = 1024;
constexpr int Ln = Hn * Wn * Zn;                 // 26624
constexpr int BWn = Bn * (Hn / 4) * (Wn / 4) * Zn; // 3328 windows (B_)
constexpr int PB = Bn * Ln;                      // 53248 rows per variable
constexpr int ROWS = Vn * PB;                    // 212992

// ---------- global -> LDS direct staging (16B per lane) ----------
DI void gload_lds16(const void* g, void* l) {
  __builtin_amdgcn_global_load_lds(
      (const __attribute__((address_space(1))) void*)g,
      (__attribute__((address_space(3))) void*)l, 16, 0, 0);
}

DI unsigned short f2bf_bits(float f) {
  __hip_bfloat16 h = __float2bfloat16(f);
  return *reinterpret_cast<unsigned short*>(&h);
}

DI float gelu_f(float x) {
  // tanh-form GELU; |diff vs exact erf-GELU| < ~1e-3, negligible after fc2
  float t = 0.7978845608028654f * (x + 0.044715f * x * x * x);
  float e = __expf(2.0f * t);
  float th = 1.0f - 2.0f / (e + 1.0f);
  return 0.5f * x * (1.0f + th);
}

// ---------- tiled weight transpose: src [V][K][N] f32 -> dst [V][N][K] bf16 ----------
// coalesced reads (256B) and writes (128B) via LDS tile. grid (N/64, K/64, V).
__global__ __launch_bounds__(256) void transpose_tile_kernel(
    const float* __restrict__ src, __hip_bfloat16* __restrict__ dst, int K, int N) {
  __shared__ float S[64][65];
  const int n0 = blockIdx.x * 64, k0 = blockIdx.y * 64, v = blockIdx.z;
  const int tc = threadIdx.x & 63, tr = threadIdx.x >> 6;  // tr 0..3
#pragma unroll
  for (int i = 0; i < 16; ++i) {
    int kk = tr + i * 4;
    S[kk][tc] = src[((size_t)v * K + k0 + kk) * N + n0 + tc];
  }
  __syncthreads();
#pragma unroll
  for (int i = 0; i < 16; ++i) {
    int nn = tr + i * 4;
    dst[((size_t)v * N + n0 + nn) * K + k0 + tc] = __float2bfloat16(S[tc][nn]);
  }
}

// ---------- LN1 fused with cyclic shift + window partition ----------
__global__ __launch_bounds__(256) void ln1_kernel(
    const float* __restrict__ x0, const float* __restrict__ x1,
    const float* __restrict__ x2i, const float* __restrict__ x3,
    const float* __restrict__ g_, const float* __restrict__ b_,
    __hip_bfloat16* __restrict__ xw) {
  int gw = blockIdx.x * 4 + (threadIdx.x >> 6);
  int lane = threadIdx.x & 63;
  int v = gw / PB;
  int rem = gw - v * PB;
  int bw = rem >> 4, nn = rem & 15;
  int zb = bw % 13;
  int t = bw / 13;
  int wb = t & 15, t2 = t >> 4;
  int hb = t2 & 7, b = t2 >> 3;
  int hs = (hb * 4 + (nn >> 2) + 30) & 31;   // (h - 2) mod 32
  int wsrc = (wb * 4 + (nn & 3) + 62) & 63;  // (w - 2) mod 64
  size_t l = (size_t)(hs * 64 + wsrc) * 13 + zb;
  const float* xv = (v == 0) ? x0 : (v == 1) ? x1 : (v == 2) ? x2i : x3;
  const float* xp = xv + ((size_t)b * Ln + l) * 256;
  float4 val = *(const float4*)(xp + lane * 4);
  float s = val.x + val.y + val.z + val.w;
  float sq = val.x * val.x + val.y * val.y + val.z * val.z + val.w * val.w;
#pragma unroll
  for (int o = 32; o; o >>= 1) {
    s += __shfl_xor(s, o);
    sq += __shfl_xor(sq, o);
  }
  float mean = s * (1.0f / 256.0f);
  float var = sq * (1.0f / 256.0f) - mean * mean;
  float rstd = rsqrtf(var + 1e-5f);
  const float* gg = g_ + v * 256 + lane * 4;
  const float* bb = b_ + v * 256 + lane * 4;
  ushort4 o4;
  o4.x = f2bf_bits((val.x - mean) * rstd * gg[0] + bb[0]);
  o4.y = f2bf_bits((val.y - mean) * rstd * gg[1] + bb[1]);
  o4.z = f2bf_bits((val.z - mean) * rstd * gg[2] + bb[2]);
  o4.w = f2bf_bits((val.w - mean) * rstd * gg[3] + bb[3]);
  *reinterpret_cast<ushort4*>(xw + (size_t)gw * 256 + lane * 4) = o4;
}

// ---------- LN2 (straight rows, x2 lives in d_out) ----------
__global__ __launch_bounds__(256) void ln2_kernel(
    const float* __restrict__ x2, const float* __restrict__ g_,
    const float* __restrict__ b_, __hip_bfloat16* __restrict__ xm) {
  int r = blockIdx.x * 4 + (threadIdx.x >> 6);
  int lane = threadIdx.x & 63;
  int v = r / PB;
  const float* xp = x2 + (size_t)r * 256;
  float4 val = *(const float4*)(xp + lane * 4);
  float s = val.x + val.y + val.z + val.w;
  float sq = val.x * val.x + val.y * val.y + val.z * val.z + val.w * val.w;
#pragma unroll
  for (int o = 32; o; o >>= 1) {
    s += __shfl_xor(s, o);
    sq += __shfl_xor(sq, o);
  }
  float mean = s * (1.0f / 256.0f);
  float var = sq * (1.0f / 256.0f) - mean * mean;
  float rstd = rsqrtf(var + 1e-5f);
  const float* gg = g_ + v * 256 + lane * 4;
  const float* bb = b_ + v * 256 + lane * 4;
  ushort4 o4;
  o4.x = f2bf_bits((val.x - mean) * rstd * gg[0] + bb[0]);
  o4.y = f2bf_bits((val.y - mean) * rstd * gg[1] + bb[1]);
  o4.z = f2bf_bits((val.z - mean) * rstd * gg[2] + bb[2]);
  o4.w = f2bf_bits((val.w - mean) * rstd * gg[3] + bb[3]);
  *reinterpret_cast<ushort4*>(xm + (size_t)r * 256 + lane * 4) = o4;
}

// ---------- windowed attention (unchanged, verified) ----------
__global__ __launch_bounds__(256) void attn_kernel(
    const __hip_bfloat16* __restrict__ qkvp, __hip_bfloat16* __restrict__ ctx) {
  __shared__ float P[4][16][17];
  int b_ = blockIdx.x;
  int v = blockIdx.y;
  int wid = threadIdx.x >> 6, lane = threadIdx.x & 63;
  int lm = lane & 15, hi = lane >> 4;
  const bf16_t* base = (const bf16_t*)qkvp + (size_t)(v * BWn + b_) * 16 * 768;
  const float scale = 0.17677669529663687f;  // 32^-0.5
  f32x4 zero = {0.f, 0.f, 0.f, 0.f};
#pragma unroll
  for (int hh = 0; hh < 2; ++hh) {
    int h = wid + 4 * hh;
    bf16x8 qf = *(const bf16x8*)(base + (size_t)lm * 768 + h * 32 + hi * 8);
    bf16x8 kf = *(const bf16x8*)(base + (size_t)lm * 768 + 256 + h * 32 + hi * 8);
    f32x4 s = __builtin_amdgcn_mfma_f32_16x16x32_bf16(qf, kf, zero, 0, 0, 0);
    float p0[4];
#pragma unroll
    for (int q = 0; q < 4; ++q) {
      float val = s[q] * scale;
      float mx = val;
#pragma unroll
      for (int o = 8; o >= 1; o >>= 1) mx = fmaxf(mx, __shfl_xor(mx, o));
      float e = expf(val - mx);
      float sum = e;
#pragma unroll
      for (int o = 8; o >= 1; o >>= 1) sum += __shfl_xor(sum, o);
      p0[q] = e / sum;
    }
#pragma unroll
    for (int q = 0; q < 4; ++q) P[wid][hi * 4 + q][lm] = p0[q];
    bf16x8 pa;
#pragma unroll
    for (int j = 0; j < 8; ++j) pa[j] = (bf16_t)0.f;
    if (hi < 2) {
#pragma unroll
      for (int j = 0; j < 8; ++j) pa[j] = (bf16_t)P[wid][lm][hi * 8 + j];
    }
#pragma unroll
    for (int dh = 0; dh < 2; ++dh) {
      bf16x8 vf;
#pragma unroll
      for (int j = 0; j < 8; ++j) vf[j] = (bf16_t)0.f;
      if (hi < 2) {
#pragma unroll
        for (int j = 0; j < 8; ++j)
          vf[j] = base[(size_t)(hi * 8 + j) * 768 + 512 + h * 32 + dh * 16 + lm];
      }
      f32x4 c = __builtin_amdgcn_mfma_f32_16x16x32_bf16(pa, vf, zero, 0, 0, 0);
#pragma unroll
      for (int q = 0; q < 4; ++q) {
        int n = hi * 4 + q;
        int d = dh * 16 + lm;
        int r = n * 4 + v;
        int vo = r >> 4, no = r & 15;
        ctx[((size_t)(vo * BWn + b_) * 16 + no) * 256 + h * 32 + d] = __float2bfloat16(c[q]);
      }
    }
  }
}

// ---------- GEMM v4: m97 structure. 128x128 tile, 4 waves (2x2), BK=64,
// single-buffered 32KB LDS + 8KB/wave epilogue staging (40KB total -> 3 blocks/CU),
// plain __syncthreads (compiler-managed waitcnt), XCD-chunked block mapping,
// LDS-staged coalesced epilogue stores.
// EPI: 0 = qkv (bias, bf16), 1 = proj (bias + window-reverse + roll + shortcut -> f32 x2),
//      2 = fc1 (bias + GELU, bf16), 3 = fc2 (bias + x2 RMW -> f32 out)
template <int EPI, int K, int N>
__global__ __launch_bounds__(256, 3) void gemm4(
    const __hip_bfloat16* __restrict__ A, const __hip_bfloat16* __restrict__ WT,
    const float* __restrict__ bias, __hip_bfloat16* __restrict__ outb,
    float* __restrict__ outf, const float* __restrict__ xi0,
    const float* __restrict__ xi1, const float* __restrict__ xi2,
    const float* __restrict__ xi3) {
  constexpr int NT = K / 64;
  constexpr int NC = N / 128;
  const int v = blockIdx.z;
  // XCD-chunked mapping: all NC col-tiles of a row-panel consecutive on ONE XCD.
  const int x = blockIdx.x;
  const int xcd = x & 7;
  const int j = x >> 3;
  const int c = j % NC;
  const int r = xcd + 8 * (j / NC);
  const int rowBase = r * 128;
  const int colBase = c * 128;

  const bf16_t* Av = (const bf16_t*)A + ((size_t)v * PB + rowBase) * K;
  const bf16_t* Wv = (const bf16_t*)WT + ((size_t)v * N + colBase) * K;

  __shared__ __align__(16) uint8_t smem[40960];
  bf16_t(*As)[64] = (bf16_t(*)[64])smem;             // [128][64]
  bf16_t(*Bs)[64] = (bf16_t(*)[64])(smem + 16384);   // [128][64]

  const int tid = threadIdx.x, wid = tid >> 6, lane = tid & 63;
  const int wr = wid >> 1, wc = wid & 1;  // 2x2 wave grid, each wave 64x64
  const int lm = lane & 15, hi = lane >> 4;
  const int rA = lane >> 3;               // 0..7 row within 8-row staging group
  const int lg = (lane & 7) ^ rA;         // pre-swizzled source granule (16B units)

  f32x4 acc[4][4];
#pragma unroll
  for (int m = 0; m < 4; ++m)
#pragma unroll
    for (int n = 0; n < 4; ++n) acc[m][n] = f32x4{0.f, 0.f, 0.f, 0.f};

  for (int t = 0; t < NT; ++t) {
    if (t) __syncthreads();  // all waves done reading previous tile
#pragma unroll
    for (int g = 0; g < 4; ++g) {
      int grp = wid * 4 + g;
      gload_lds16(Av + (size_t)(grp * 8 + rA) * K + t * 64 + lg * 8, &As[grp * 8][0]);
    }
#pragma unroll
    for (int g = 0; g < 4; ++g) {
      int grp = wid * 4 + g;
      gload_lds16(Wv + (size_t)(grp * 8 + rA) * K + t * 64 + lg * 8, &Bs[grp * 8][0]);
    }
    __syncthreads();  // compiler drains vmcnt before barrier
#pragma unroll
    for (int kk = 0; kk < 2; ++kk) {
      bf16x8 af[4], bfv[4];
#pragma unroll
      for (int m = 0; m < 4; ++m) {
        const int rr = wr * 64 + m * 16 + lm;
        af[m] = *(const bf16x8*)&As[rr][((kk * 4 + hi) ^ (lm & 7)) * 8];
      }
#pragma unroll
      for (int n = 0; n < 4; ++n) {
        const int rr = wc * 64 + n * 16 + lm;
        bfv[n] = *(const bf16x8*)&Bs[rr][((kk * 4 + hi) ^ (lm & 7)) * 8];
      }
#pragma unroll
      for (int m = 0; m < 4; ++m)
#pragma unroll
        for (int n = 0; n < 4; ++n)
          acc[m][n] = __builtin_amdgcn_mfma_f32_16x16x32_bf16(af[m], bfv[n], acc[m][n], 0, 0, 0);
    }
  }

  __syncthreads();  // LDS now free for epilogue staging
  uint8_t* ep = smem + wid * 10240;  // per-wave region (<=9216B used)

  if constexpr (EPI == 0 || EPI == 2) {
    // bf16 output with bias (+GELU for fc1), staged for 16B/lane coalesced stores
    ushort(*E)[72] = (ushort(*)[72])ep;  // 64 x 72 (pad 8) = 9216B
    float bcol[4];
#pragma unroll
    for (int n = 0; n < 4; ++n) bcol[n] = bias[v * N + colBase + wc * 64 + n * 16 + lm];
#pragma unroll
    for (int m = 0; m < 4; ++m)
#pragma unroll
      for (int q = 0; q < 4; ++q) {
        int lr = m * 16 + hi * 4 + q;
#pragma unroll
        for (int n = 0; n < 4; ++n) {
          float val = acc[m][n][q] + bcol[n];
          if constexpr (EPI == 2) val = gelu_f(val);
          E[lr][n * 16 + lm] = f2bf_bits(val);
        }
      }
    const int pr = lane >> 3, pc = lane & 7;
#pragma unroll
    for (int p = 0; p < 8; ++p) {
      int lr = p * 8 + pr;
      bf16x8 val = *(const bf16x8*)&E[lr][pc * 8];
      size_t grow = (size_t)v * PB + rowBase + wr * 64 + lr;
      int gcol = colBase + wc * 64 + pc * 8;
      *(bf16x8*)&outb[grow * N + gcol] = val;
    }
  } else {
    // f32 paths, staged in two 32-col halves
    float(*F)[36] = (float(*)[36])ep;  // 64 x 36 (pad 4) = 9216B
    const int pr = lane >> 3, pc = lane & 7;
#pragma unroll
    for (int h2 = 0; h2 < 2; ++h2) {
#pragma unroll
      for (int m = 0; m < 4; ++m)
#pragma unroll
        for (int q = 0; q < 4; ++q) {
          int lr = m * 16 + hi * 4 + q;
#pragma unroll
          for (int n2 = 0; n2 < 2; ++n2) F[lr][n2 * 16 + lm] = acc[m][h2 * 2 + n2][q];
        }
#pragma unroll
      for (int p = 0; p < 8; ++p) {
        int lr = p * 8 + pr;
        f32x4 a4 = *(const f32x4*)&F[lr][pc * 4];
        int rowv = rowBase + wr * 64 + lr;
        int gcol = colBase + wc * 64 + h2 * 32 + pc * 4;
        f32x4 b4 = *(const f32x4*)&bias[v * N + gcol];
        if constexpr (EPI == 1) {
          int b_ = rowv >> 4, nn = rowv & 15;
          int zb = b_ % 13;
          int tt = b_ / 13;
          int wb = tt & 15, tt2 = tt >> 4;
          int hb = tt2 & 7, bb = tt2 >> 3;
          int h2v = (hb * 4 + (nn >> 2) + 2) & 31;  // window reverse + roll(+2)
          int w2v = (wb * 4 + (nn & 3) + 2) & 63;
          size_t l = (size_t)(h2v * 64 + w2v) * 13 + zb;
          const float* xv = (v == 0) ? xi0 : (v == 1) ? xi1 : (v == 2) ? xi2 : xi3;
          f32x4 x4 = *(const f32x4*)(xv + ((size_t)bb * Ln + l) * 256 + gcol);
          f32x4 o4 = a4 + b4 + x4;
          *(f32x4*)(outf + (((size_t)v * Bn + bb) * Ln + l) * 256 + gcol) = o4;
        } else {  // EPI == 3: RMW residual
          float* o = outf + ((size_t)v * PB + rowv) * 256 + gcol;
          f32x4 cur = *(const f32x4*)o;
          f32x4 o4 = cur + a4 + b4;
          *(f32x4*)o = o4;
        }
      }
      if (h2 == 0) __builtin_amdgcn_s_waitcnt(0);  // drain lgkm before overwriting F
    }
  }
}

extern "C" void kernel_launch(void* const* d_in, const int* in_sizes, int n_in,
                              void* d_out, int out_size, void* d_ws, size_t ws_size,
                              hipStream_t stream) {
  const float* x0 = (const float*)d_in[0];
  const float* x1 = (const float*)d_in[1];
  const float* x2i = (const float*)d_in[2];
  const float* x3 = (const float*)d_in[3];
  const float* qkv_w = (const float*)d_in[4];
  const float* qkv_b = (const float*)d_in[5];
  const float* proj_w = (const float*)d_in[6];
  const float* proj_b = (const float*)d_in[7];
  const float* n1g = (const float*)d_in[8];
  const float* n1b = (const float*)d_in[9];
  const float* n2g = (const float*)d_in[10];
  const float* n2b = (const float*)d_in[11];
  const float* fc1_w = (const float*)d_in[12];
  const float* fc1_b = (const float*)d_in[13];
  const float* fc2_w = (const float*)d_in[14];
  const float* fc2_b = (const float*)d_in[15];
  float* out = (float*)d_out;  // doubles as x2 buffer

  uint8_t* ws = (uint8_t*)d_ws;
  size_t off = 0;
  auto alloc = [&](size_t bytes) -> void* {
    void* p = ws + off;
    off += (bytes + 255) & ~(size_t)255;
    return p;
  };
  __hip_bfloat16* wqkvT = (__hip_bfloat16*)alloc((size_t)Vn * Cn * 768 * 2);
  __hip_bfloat16* wprojT = (__hip_bfloat16*)alloc((size_t)Vn * Cn * Cn * 2);
  __hip_bfloat16* wfc1T = (__hip_bfloat16*)alloc((size_t)Vn * Cn * HIDn * 2);
  __hip_bfloat16* wfc2T = (__hip_bfloat16*)alloc((size_t)Vn * HIDn * Cn * 2);
  __hip_bfloat16* xw = (__hip_bfloat16*)alloc((size_t)ROWS * Cn * 2);     // xw / ctx / xm
  __hip_bfloat16* qkvb = (__hip_bfloat16*)alloc((size_t)ROWS * HIDn * 2); // qkv / h

  transpose_tile_kernel<<<dim3(768 / 64, 256 / 64, Vn), 256, 0, stream>>>(qkv_w, wqkvT, 256, 768);
  transpose_tile_kernel<<<dim3(256 / 64, 256 / 64, Vn), 256, 0, stream>>>(proj_w, wprojT, 256, 256);
  transpose_tile_kernel<<<dim3(1024 / 64, 256 / 64, Vn), 256, 0, stream>>>(fc1_w, wfc1T, 256, 1024);
  transpose_tile_kernel<<<dim3(256 / 64, 1024 / 64, Vn), 256, 0, stream>>>(fc2_w, wfc2T, 1024, 256);

  ln1_kernel<<<ROWS / 4, 256, 0, stream>>>(x0, x1, x2i, x3, n1g, n1b, xw);

  gemm4<0, 256, 768><<<dim3(416 * 6, 1, Vn), 256, 0, stream>>>(
      xw, wqkvT, qkv_b, qkvb, nullptr, nullptr, nullptr, nullptr, nullptr);

  attn_kernel<<<dim3(BWn, Vn), 256, 0, stream>>>(qkvb, xw /*ctx*/);

  gemm4<1, 256, 256><<<dim3(416 * 2, 1, Vn), 256, 0, stream>>>(
      xw /*ctx*/, wprojT, proj_b, nullptr, out /*x2*/, x0, x1, x2i, x3);

  ln2_kernel<<<ROWS / 4, 256, 0, stream>>>(out /*x2*/, n2g, n2b, xw /*xm*/);

  gemm4<2, 256, 1024><<<dim3(416 * 8, 1, Vn), 256, 0, stream>>>(
      xw /*xm*/, wfc1T, fc1_b, qkvb /*h*/, nullptr, nullptr, nullptr, nullptr, nullptr);

  gemm4<3, 1024, 256><<<dim3(416 * 2, 1, Vn), 256, 0, stream>>>(
      qkvb /*h*/, wfc2T, fc2_b, nullptr, out, nullptr, nullptr, nullptr, nullptr);
}

// Round 5
// 924.559 us; speedup vs baseline: 1.2281x; 1.0350x over previous
//
#include <hip/hip_runtime.h>
#include <hip/hip_bf16.h>
#include <cstdint>
#include <cstddef>

#define DI __device__ __forceinline__

typedef __bf16 bf16_t;
typedef bf16_t bf16x8 __attribute__((ext_vector_type(8)));
typedef float f32x4 __attribute__((ext_vector_type(4)));

constexpr int Vn = 4, Bn = 2, Hn = 32, Wn = 64, Zn = 13, Cn = 256, HIDn = 1024;
constexpr int Ln = Hn * Wn * Zn;                 // 26624
constexpr int BWn = Bn * (Hn / 4) * (Wn / 4) * Zn; // 3328 windows (B_)
constexpr int PB = Bn * Ln;                      // 53248 rows per variable
constexpr int ROWS = Vn * PB;                    // 212992

// ---------- global -> LDS direct staging (16B per lane) ----------
DI void gload_lds16(const void* g, void* l) {
  __builtin_amdgcn_global_load_lds(
      (const __attribute__((address_space(1))) void*)g,
      (__attribute__((address_space(3))) void*)l, 16, 0, 0);
}

DI unsigned short f2bf_bits(float f) {
  __hip_bfloat16 h = __float2bfloat16(f);
  return *reinterpret_cast<unsigned short*>(&h);
}

DI float gelu_f(float x) {
  // sigmoid-form tanh-GELU: x * sigmoid(1.5957691*(x + 0.044715 x^3))
  // uses v_rcp_f32 instead of IEEE divide (epilogue was VALU-bound on v_div_*)
  float u = x * x;
  float w = x * fmaf(0.044715f, u, 1.0f);
  float e = __expf(-1.5957691216057308f * w);
  return x * __builtin_amdgcn_rcpf(1.0f + e);
}

// ---------- tiled weight transpose: src [V][K][N] f32 -> dst [V][N][K] bf16 ----------
__global__ __launch_bounds__(256) void transpose_tile_kernel(
    const float* __restrict__ src, __hip_bfloat16* __restrict__ dst, int K, int N) {
  __shared__ float S[64][65];
  const int n0 = blockIdx.x * 64, k0 = blockIdx.y * 64, v = blockIdx.z;
  const int tc = threadIdx.x & 63, tr = threadIdx.x >> 6;  // tr 0..3
#pragma unroll
  for (int i = 0; i < 16; ++i) {
    int kk = tr + i * 4;
    S[kk][tc] = src[((size_t)v * K + k0 + kk) * N + n0 + tc];
  }
  __syncthreads();
#pragma unroll
  for (int i = 0; i < 16; ++i) {
    int nn = tr + i * 4;
    dst[((size_t)v * N + n0 + nn) * K + k0 + tc] = __float2bfloat16(S[tc][nn]);
  }
}

// ---------- LN1 fused with cyclic shift + window partition ----------
__global__ __launch_bounds__(256) void ln1_kernel(
    const float* __restrict__ x0, const float* __restrict__ x1,
    const float* __restrict__ x2i, const float* __restrict__ x3,
    const float* __restrict__ g_, const float* __restrict__ b_,
    __hip_bfloat16* __restrict__ xw) {
  int gw = blockIdx.x * 4 + (threadIdx.x >> 6);
  int lane = threadIdx.x & 63;
  int v = gw / PB;
  int rem = gw - v * PB;
  int bw = rem >> 4, nn = rem & 15;
  int zb = bw % 13;
  int t = bw / 13;
  int wb = t & 15, t2 = t >> 4;
  int hb = t2 & 7, b = t2 >> 3;
  int hs = (hb * 4 + (nn >> 2) + 30) & 31;   // (h - 2) mod 32
  int wsrc = (wb * 4 + (nn & 3) + 62) & 63;  // (w - 2) mod 64
  size_t l = (size_t)(hs * 64 + wsrc) * 13 + zb;
  const float* xv = (v == 0) ? x0 : (v == 1) ? x1 : (v == 2) ? x2i : x3;
  const float* xp = xv + ((size_t)b * Ln + l) * 256;
  float4 val = *(const float4*)(xp + lane * 4);
  float s = val.x + val.y + val.z + val.w;
  float sq = val.x * val.x + val.y * val.y + val.z * val.z + val.w * val.w;
#pragma unroll
  for (int o = 32; o; o >>= 1) {
    s += __shfl_xor(s, o);
    sq += __shfl_xor(sq, o);
  }
  float mean = s * (1.0f / 256.0f);
  float var = sq * (1.0f / 256.0f) - mean * mean;
  float rstd = rsqrtf(var + 1e-5f);
  const float* gg = g_ + v * 256 + lane * 4;
  const float* bb = b_ + v * 256 + lane * 4;
  ushort4 o4;
  o4.x = f2bf_bits((val.x - mean) * rstd * gg[0] + bb[0]);
  o4.y = f2bf_bits((val.y - mean) * rstd * gg[1] + bb[1]);
  o4.z = f2bf_bits((val.z - mean) * rstd * gg[2] + bb[2]);
  o4.w = f2bf_bits((val.w - mean) * rstd * gg[3] + bb[3]);
  *reinterpret_cast<ushort4*>(xw + (size_t)gw * 256 + lane * 4) = o4;
}

// ---------- LN2 (straight rows, x2 lives in d_out) ----------
__global__ __launch_bounds__(256) void ln2_kernel(
    const float* __restrict__ x2, const float* __restrict__ g_,
    const float* __restrict__ b_, __hip_bfloat16* __restrict__ xm) {
  int r = blockIdx.x * 4 + (threadIdx.x >> 6);
  int lane = threadIdx.x & 63;
  int v = r / PB;
  const float* xp = x2 + (size_t)r * 256;
  float4 val = *(const float4*)(xp + lane * 4);
  float s = val.x + val.y + val.z + val.w;
  float sq = val.x * val.x + val.y * val.y + val.z * val.z + val.w * val.w;
#pragma unroll
  for (int o = 32; o; o >>= 1) {
    s += __shfl_xor(s, o);
    sq += __shfl_xor(sq, o);
  }
  float mean = s * (1.0f / 256.0f);
  float var = sq * (1.0f / 256.0f) - mean * mean;
  float rstd = rsqrtf(var + 1e-5f);
  const float* gg = g_ + v * 256 + lane * 4;
  const float* bb = b_ + v * 256 + lane * 4;
  ushort4 o4;
  o4.x = f2bf_bits((val.x - mean) * rstd * gg[0] + bb[0]);
  o4.y = f2bf_bits((val.y - mean) * rstd * gg[1] + bb[1]);
  o4.z = f2bf_bits((val.z - mean) * rstd * gg[2] + bb[2]);
  o4.w = f2bf_bits((val.w - mean) * rstd * gg[3] + bb[3]);
  *reinterpret_cast<ushort4*>(xm + (size_t)r * 256 + lane * 4) = o4;
}

// ---------- windowed attention ----------
__global__ __launch_bounds__(256) void attn_kernel(
    const __hip_bfloat16* __restrict__ qkvp, __hip_bfloat16* __restrict__ ctx) {
  __shared__ float P[4][16][17];
  int b_ = blockIdx.x;
  int v = blockIdx.y;
  int wid = threadIdx.x >> 6, lane = threadIdx.x & 63;
  int lm = lane & 15, hi = lane >> 4;
  const bf16_t* base = (const bf16_t*)qkvp + (size_t)(v * BWn + b_) * 16 * 768;
  const float scale = 0.17677669529663687f;  // 32^-0.5
  f32x4 zero = {0.f, 0.f, 0.f, 0.f};
#pragma unroll
  for (int hh = 0; hh < 2; ++hh) {
    int h = wid + 4 * hh;
    bf16x8 qf = *(const bf16x8*)(base + (size_t)lm * 768 + h * 32 + hi * 8);
    bf16x8 kf = *(const bf16x8*)(base + (size_t)lm * 768 + 256 + h * 32 + hi * 8);
    f32x4 s = __builtin_amdgcn_mfma_f32_16x16x32_bf16(qf, kf, zero, 0, 0, 0);
    float p0[4];
#pragma unroll
    for (int q = 0; q < 4; ++q) {
      float val = s[q] * scale;
      float mx = val;
#pragma unroll
      for (int o = 8; o >= 1; o >>= 1) mx = fmaxf(mx, __shfl_xor(mx, o));
      float e = __expf(val - mx);
      float sum = e;
#pragma unroll
      for (int o = 8; o >= 1; o >>= 1) sum += __shfl_xor(sum, o);
      p0[q] = e * __builtin_amdgcn_rcpf(sum);
    }
#pragma unroll
    for (int q = 0; q < 4; ++q) P[wid][hi * 4 + q][lm] = p0[q];
    bf16x8 pa;
#pragma unroll
    for (int j = 0; j < 8; ++j) pa[j] = (bf16_t)0.f;
    if (hi < 2) {
#pragma unroll
      for (int j = 0; j < 8; ++j) pa[j] = (bf16_t)P[wid][lm][hi * 8 + j];
    }
#pragma unroll
    for (int dh = 0; dh < 2; ++dh) {
      bf16x8 vf;
#pragma unroll
      for (int j = 0; j < 8; ++j) vf[j] = (bf16_t)0.f;
      if (hi < 2) {
#pragma unroll
        for (int j = 0; j < 8; ++j)
          vf[j] = base[(size_t)(hi * 8 + j) * 768 + 512 + h * 32 + dh * 16 + lm];
      }
      f32x4 c = __builtin_amdgcn_mfma_f32_16x16x32_bf16(pa, vf, zero, 0, 0, 0);
#pragma unroll
      for (int q = 0; q < 4; ++q) {
        int n = hi * 4 + q;
        int d = dh * 16 + lm;
        int r = n * 4 + v;
        int vo = r >> 4, no = r & 15;
        ctx[((size_t)(vo * BWn + b_) * 16 + no) * 256 + h * 32 + d] = __float2bfloat16(c[q]);
      }
    }
  }
}

// ---------- GEMM v4: m97 structure. 128x128 tile, 4 waves (2x2), BK=64,
// single-buffered 32KB LDS + per-wave epilogue staging (40KB total -> 3 blocks/CU),
// XCD-chunked block mapping, LDS-staged coalesced epilogue stores.
// EPI: 0 = qkv (bias, bf16), 1 = proj (bias + window-reverse + roll + shortcut -> f32 x2),
//      2 = fc1 (bias + GELU, bf16), 3 = fc2 (bias + x2 RMW -> f32 out)
template <int EPI, int K, int N>
__global__ __launch_bounds__(256, 3) void gemm4(
    const __hip_bfloat16* __restrict__ A, const __hip_bfloat16* __restrict__ WT,
    const float* __restrict__ bias, __hip_bfloat16* __restrict__ outb,
    float* __restrict__ outf, const float* __restrict__ xi0,
    const float* __restrict__ xi1, const float* __restrict__ xi2,
    const float* __restrict__ xi3) {
  constexpr int NT = K / 64;
  constexpr int NC = N / 128;
  const int v = blockIdx.z;
  // XCD-chunked mapping: all NC col-tiles of a row-panel consecutive on ONE XCD.
  const int x = blockIdx.x;
  const int xcd = x & 7;
  const int j = x >> 3;
  const int c = j % NC;
  const int r = xcd + 8 * (j / NC);
  const int rowBase = r * 128;
  const int colBase = c * 128;

  const bf16_t* Av = (const bf16_t*)A + ((size_t)v * PB + rowBase) * K;
  const bf16_t* Wv = (const bf16_t*)WT + ((size_t)v * N + colBase) * K;

  __shared__ __align__(16) uint8_t smem[40960];
  bf16_t(*As)[64] = (bf16_t(*)[64])smem;             // [128][64]
  bf16_t(*Bs)[64] = (bf16_t(*)[64])(smem + 16384);   // [128][64]

  const int tid = threadIdx.x, wid = tid >> 6, lane = tid & 63;
  const int wr = wid >> 1, wc = wid & 1;  // 2x2 wave grid, each wave 64x64
  const int lm = lane & 15, hi = lane >> 4;
  const int rA = lane >> 3;               // 0..7 row within 8-row staging group
  const int lg = (lane & 7) ^ rA;         // pre-swizzled source granule (16B units)

  f32x4 acc[4][4];
#pragma unroll
  for (int m = 0; m < 4; ++m)
#pragma unroll
    for (int n = 0; n < 4; ++n) acc[m][n] = f32x4{0.f, 0.f, 0.f, 0.f};

  for (int t = 0; t < NT; ++t) {
    if (t) __syncthreads();  // all waves done reading previous tile
#pragma unroll
    for (int g = 0; g < 4; ++g) {
      int grp = wid * 4 + g;
      gload_lds16(Av + (size_t)(grp * 8 + rA) * K + t * 64 + lg * 8, &As[grp * 8][0]);
    }
#pragma unroll
    for (int g = 0; g < 4; ++g) {
      int grp = wid * 4 + g;
      gload_lds16(Wv + (size_t)(grp * 8 + rA) * K + t * 64 + lg * 8, &Bs[grp * 8][0]);
    }
    __syncthreads();  // compiler drains vmcnt before barrier
#pragma unroll
    for (int kk = 0; kk < 2; ++kk) {
      bf16x8 af[4], bfv[4];
#pragma unroll
      for (int m = 0; m < 4; ++m) {
        const int rr = wr * 64 + m * 16 + lm;
        af[m] = *(const bf16x8*)&As[rr][((kk * 4 + hi) ^ (lm & 7)) * 8];
      }
#pragma unroll
      for (int n = 0; n < 4; ++n) {
        const int rr = wc * 64 + n * 16 + lm;
        bfv[n] = *(const bf16x8*)&Bs[rr][((kk * 4 + hi) ^ (lm & 7)) * 8];
      }
#pragma unroll
      for (int m = 0; m < 4; ++m)
#pragma unroll
        for (int n = 0; n < 4; ++n)
          acc[m][n] = __builtin_amdgcn_mfma_f32_16x16x32_bf16(af[m], bfv[n], acc[m][n], 0, 0, 0);
    }
  }

  __syncthreads();  // LDS now free for epilogue staging
  uint8_t* ep = smem + wid * 10240;  // per-wave region (<=9216B used)

  if constexpr (EPI == 0 || EPI == 2) {
    // bf16 output with bias (+GELU for fc1), staged for 16B/lane coalesced stores
    ushort(*E)[72] = (ushort(*)[72])ep;  // 64 x 72 (pad 8) = 9216B
    float bcol[4];
#pragma unroll
    for (int n = 0; n < 4; ++n) bcol[n] = bias[v * N + colBase + wc * 64 + n * 16 + lm];
#pragma unroll
    for (int m = 0; m < 4; ++m)
#pragma unroll
      for (int q = 0; q < 4; ++q) {
        int lr = m * 16 + hi * 4 + q;
#pragma unroll
        for (int n = 0; n < 4; ++n) {
          float val = acc[m][n][q] + bcol[n];
          if constexpr (EPI == 2) val = gelu_f(val);
          E[lr][n * 16 + lm] = f2bf_bits(val);
        }
      }
    const int pr = lane >> 3, pc = lane & 7;
#pragma unroll
    for (int p = 0; p < 8; ++p) {
      int lr = p * 8 + pr;
      bf16x8 val = *(const bf16x8*)&E[lr][pc * 8];
      size_t grow = (size_t)v * PB + rowBase + wr * 64 + lr;
      int gcol = colBase + wc * 64 + pc * 8;
      *(bf16x8*)&outb[grow * N + gcol] = val;
    }
  } else {
    // f32 paths, staged in two 32-col halves
    float(*F)[36] = (float(*)[36])ep;  // 64 x 36 (pad 4) = 9216B
    const int pr = lane >> 3, pc = lane & 7;
#pragma unroll
    for (int h2 = 0; h2 < 2; ++h2) {
#pragma unroll
      for (int m = 0; m < 4; ++m)
#pragma unroll
        for (int q = 0; q < 4; ++q) {
          int lr = m * 16 + hi * 4 + q;
#pragma unroll
          for (int n2 = 0; n2 < 2; ++n2) F[lr][n2 * 16 + lm] = acc[m][h2 * 2 + n2][q];
        }
#pragma unroll
      for (int p = 0; p < 8; ++p) {
        int lr = p * 8 + pr;
        f32x4 a4 = *(const f32x4*)&F[lr][pc * 4];
        int rowv = rowBase + wr * 64 + lr;
        int gcol = colBase + wc * 64 + h2 * 32 + pc * 4;
        f32x4 b4 = *(const f32x4*)&bias[v * N + gcol];
        if constexpr (EPI == 1) {
          int b_ = rowv >> 4, nn = rowv & 15;
          int zb = b_ % 13;
          int tt = b_ / 13;
          int wb = tt & 15, tt2 = tt >> 4;
          int hb = tt2 & 7, bb = tt2 >> 3;
          int h2v = (hb * 4 + (nn >> 2) + 2) & 31;  // window reverse + roll(+2)
          int w2v = (wb * 4 + (nn & 3) + 2) & 63;
          size_t l = (size_t)(h2v * 64 + w2v) * 13 + zb;
          const float* xv = (v == 0) ? xi0 : (v == 1) ? xi1 : (v == 2) ? xi2 : xi3;
          f32x4 x4 = *(const f32x4*)(xv + ((size_t)bb * Ln + l) * 256 + gcol);
          f32x4 o4 = a4 + b4 + x4;
          *(f32x4*)(outf + (((size_t)v * Bn + bb) * Ln + l) * 256 + gcol) = o4;
        } else {  // EPI == 3: RMW residual
          float* o = outf + ((size_t)v * PB + rowv) * 256 + gcol;
          f32x4 cur = *(const f32x4*)o;
          f32x4 o4 = cur + a4 + b4;
          *(f32x4*)o = o4;
        }
      }
      if (h2 == 0) __builtin_amdgcn_s_waitcnt(0);  // drain lgkm before overwriting F
    }
  }
}

extern "C" void kernel_launch(void* const* d_in, const int* in_sizes, int n_in,
                              void* d_out, int out_size, void* d_ws, size_t ws_size,
                              hipStream_t stream) {
  const float* x0 = (const float*)d_in[0];
  const float* x1 = (const float*)d_in[1];
  const float* x2i = (const float*)d_in[2];
  const float* x3 = (const float*)d_in[3];
  const float* qkv_w = (const float*)d_in[4];
  const float* qkv_b = (const float*)d_in[5];
  const float* proj_w = (const float*)d_in[6];
  const float* proj_b = (const float*)d_in[7];
  const float* n1g = (const float*)d_in[8];
  const float* n1b = (const float*)d_in[9];
  const float* n2g = (const float*)d_in[10];
  const float* n2b = (const float*)d_in[11];
  const float* fc1_w = (const float*)d_in[12];
  const float* fc1_b = (const float*)d_in[13];
  const float* fc2_w = (const float*)d_in[14];
  const float* fc2_b = (const float*)d_in[15];
  float* out = (float*)d_out;  // doubles as x2 buffer

  uint8_t* ws = (uint8_t*)d_ws;
  size_t off = 0;
  auto alloc = [&](size_t bytes) -> void* {
    void* p = ws + off;
    off += (bytes + 255) & ~(size_t)255;
    return p;
  };
  __hip_bfloat16* wqkvT = (__hip_bfloat16*)alloc((size_t)Vn * Cn * 768 * 2);
  __hip_bfloat16* wprojT = (__hip_bfloat16*)alloc((size_t)Vn * Cn * Cn * 2);
  __hip_bfloat16* wfc1T = (__hip_bfloat16*)alloc((size_t)Vn * Cn * HIDn * 2);
  __hip_bfloat16* wfc2T = (__hip_bfloat16*)alloc((size_t)Vn * HIDn * Cn * 2);
  __hip_bfloat16* xw = (__hip_bfloat16*)alloc((size_t)ROWS * Cn * 2);     // xw / ctx / xm
  __hip_bfloat16* qkvb = (__hip_bfloat16*)alloc((size_t)ROWS * HIDn * 2); // qkv / h

  transpose_tile_kernel<<<dim3(768 / 64, 256 / 64, Vn), 256, 0, stream>>>(qkv_w, wqkvT, 256, 768);
  transpose_tile_kernel<<<dim3(256 / 64, 256 / 64, Vn), 256, 0, stream>>>(proj_w, wprojT, 256, 256);
  transpose_tile_kernel<<<dim3(1024 / 64, 256 / 64, Vn), 256, 0, stream>>>(fc1_w, wfc1T, 256, 1024);
  transpose_tile_kernel<<<dim3(256 / 64, 1024 / 64, Vn), 256, 0, stream>>>(fc2_w, wfc2T, 1024, 256);

  ln1_kernel<<<ROWS / 4, 256, 0, stream>>>(x0, x1, x2i, x3, n1g, n1b, xw);

  gemm4<0, 256, 768><<<dim3(416 * 6, 1, Vn), 256, 0, stream>>>(
      xw, wqkvT, qkv_b, qkvb, nullptr, nullptr, nullptr, nullptr, nullptr);

  attn_kernel<<<dim3(BWn, Vn), 256, 0, stream>>>(qkvb, xw /*ctx*/);

  gemm4<1, 256, 256><<<dim3(416 * 2, 1, Vn), 256, 0, stream>>>(
      xw /*ctx*/, wprojT, proj_b, nullptr, out /*x2*/, x0, x1, x2i, x3);

  ln2_kernel<<<ROWS / 4, 256, 0, stream>>>(out /*x2*/, n2g, n2b, xw /*xm*/);

  gemm4<2, 256, 1024><<<dim3(416 * 8, 1, Vn), 256, 0, stream>>>(
      xw /*xm*/, wfc1T, fc1_b, qkvb /*h*/, nullptr, nullptr, nullptr, nullptr, nullptr);

  gemm4<3, 1024, 256><<<dim3(416 * 2, 1, Vn), 256, 0, stream>>>(
      qkvb /*h*/, wfc2T, fc2_b, nullptr, out, nullptr, nullptr, nullptr, nullptr);
}